// Round 3
// baseline (87.227 us; speedup 1.0000x reference)
//
#include <hip/hip_runtime.h>
#include <hip/hip_bf16.h>

typedef unsigned short u16;
typedef __attribute__((ext_vector_type(8))) short bhalf8;
typedef __attribute__((ext_vector_type(4))) float fx4;

struct __align__(8) US4 { u16 v[4]; };

__device__ __forceinline__ u16 f2bf(float x) {
  union { float f; unsigned int u; } c; c.f = x;
  unsigned int r = c.u + 0x7FFFu + ((c.u >> 16) & 1u);
  return (u16)(r >> 16);
}

__device__ __forceinline__ void gload16(const void* g, void* l) {
  __builtin_amdgcn_global_load_lds((const __attribute__((address_space(1))) void*)g,
                                   (__attribute__((address_space(3))) void*)l,
                                   16, 0, 0);
}

#define MFMA16(a, b, c) __builtin_amdgcn_mfma_f32_16x16x32_bf16((a), (b), (c), 0, 0, 0)
#define FENCE() asm volatile("" ::: "memory")

// ---------------- input conversion ----------------
__global__ void k_conv(const float* __restrict__ in, u16* __restrict__ out, int n4) {
  int i = blockIdx.x * 256 + threadIdx.x;
  if (i < n4) {
    float4 v = ((const float4*)in)[i];
    US4 o;
    o.v[0] = f2bf(v.x); o.v[1] = f2bf(v.y); o.v[2] = f2bf(v.z); o.v[3] = f2bf(v.w);
    ((US4*)out)[i] = o;
  }
}

// transpose [R][C] f32 -> [C][R] bf16, 64x64 tiles.
// remap!=0: output rows >=512 get per-head K/V interleave:
//   K col c in [512,1024)  -> 512 + h*128 +      (c-512)%64
//   V col c in [1024,1536) -> 512 + h*128 + 64 + (c-1024)%64
__global__ void k_transpose(const float* __restrict__ in, u16* __restrict__ out,
                            int R, int C, int rtiles, int remap) {
  __shared__ float tile[64][65];
  const int bx = blockIdx.x;
  const int rt = bx % rtiles, ct = bx / rtiles;
  const int r0 = rt * 64, c0 = ct * 64;
  const int t = threadIdx.x;
  #pragma unroll
  for (int i = 0; i < 16; ++i) {
    int e = i * 256 + t;
    int rr = e >> 6, cc = e & 63;
    tile[rr][cc] = in[(r0 + rr) * C + c0 + cc];
  }
  __syncthreads();
  #pragma unroll
  for (int i = 0; i < 16; ++i) {
    int e = i * 256 + t;
    int rr = e >> 6, cc = e & 63;
    int orow = c0 + rr;
    if (remap && orow >= 512) {
      int region = (orow - 512) >> 9;       // 0=K, 1=V
      int within = (orow - 512) & 511;
      int h = within >> 6;
      orow = 512 + h * 128 + region * 64 + (within & 63);
    }
    out[orow * R + r0 + cc] = f2bf(tile[cc][rr]);
  }
}

// ---------------- pipelined 256x128 GEMM core: BK=64, 3 LDS bufs, depth-2 prefetch ----------------
// lds: buf i at i*49152 (A 32KB at +0, B 16KB at +32768). K=512 -> 8 K-tiles.
// counted vmcnt(6) at tile end: tile t+2's 6 loads stay in flight (T4).
__device__ __forceinline__ void gemm_core2(const char* Ab, const char* Bb,
                                           char* lds, fx4 acc[4][4]) {
  const int t = threadIdx.x;
  const int w = t >> 6, l = t & 63;
  const int wm = w >> 1, wn = w & 1;   // 4 M-groups x 2 N-groups

  #define STAGE_A(buf, kt, j) do {                                   \
    int off_ = ((j) * 512 + t) * 16;                                 \
    int row_ = off_ >> 7;                                            \
    int scol_ = (off_ & 127) ^ ((row_ & 7) << 4);                    \
    gload16(Ab + row_ * 1024 + (kt) * 128 + scol_,                   \
            lds + (buf) * 49152 + off_);                             \
  } while (0)
  #define STAGE_B(buf, kt, j) do {                                   \
    int off_ = ((j) * 512 + t) * 16;                                 \
    int row_ = off_ >> 7;                                            \
    int scol_ = (off_ & 127) ^ ((row_ & 7) << 4);                    \
    gload16(Bb + row_ * 1024 + (kt) * 128 + scol_,                   \
            lds + (buf) * 49152 + 32768 + off_);                     \
  } while (0)

  // prologue: stage tiles 0,1
  #pragma unroll
  for (int j = 0; j < 4; ++j) STAGE_A(0, 0, j);
  #pragma unroll
  for (int j = 0; j < 2; ++j) STAGE_B(0, 0, j);
  #pragma unroll
  for (int j = 0; j < 4; ++j) STAGE_A(1, 1, j);
  #pragma unroll
  for (int j = 0; j < 2; ++j) STAGE_B(1, 1, j);
  asm volatile("s_waitcnt vmcnt(6)" ::: "memory");   // tile 0 landed
  __builtin_amdgcn_s_barrier();
  FENCE();
  __builtin_amdgcn_sched_barrier(0);

  #pragma unroll 1
  for (int kt = 0; kt < 8; ++kt) {
    const int p = kt % 3;
    const char* As = lds + p * 49152;
    const char* Bs = As + 32768;
    if (kt < 6) {                       // stage tile kt+2 into buf holding tile kt-1 (free)
      const int np = (kt + 2) % 3;
      STAGE_A(np, kt + 2, 0); STAGE_A(np, kt + 2, 1);
      STAGE_B(np, kt + 2, 0);
      STAGE_A(np, kt + 2, 2); STAGE_A(np, kt + 2, 3);
      STAGE_B(np, kt + 2, 1);
    }
    #pragma unroll
    for (int ks = 0; ks < 2; ++ks) {
      bhalf8 af[4], bfv[4];
      const int kbyte = ks * 64 + ((l >> 4) * 16);
      #pragma unroll
      for (int f = 0; f < 4; ++f) {
        int ra = wm * 64 + f * 16 + (l & 15);
        af[f] = *(const bhalf8*)(As + ra * 128 + (kbyte ^ ((ra & 7) << 4)));
        int rb = wn * 64 + f * 16 + (l & 15);
        bfv[f] = *(const bhalf8*)(Bs + rb * 128 + (kbyte ^ ((rb & 7) << 4)));
      }
      __builtin_amdgcn_s_setprio(1);
      #pragma unroll
      for (int fm = 0; fm < 4; ++fm)
        #pragma unroll
        for (int fn = 0; fn < 4; ++fn)
          acc[fm][fn] = MFMA16(af[fm], bfv[fn], acc[fm][fn]);
      __builtin_amdgcn_s_setprio(0);
    }
    if (kt < 6) asm volatile("s_waitcnt vmcnt(6)" ::: "memory");  // tile kt+1 landed, kt+2 in flight
    else        asm volatile("s_waitcnt vmcnt(0)" ::: "memory");
    __builtin_amdgcn_s_barrier();
    FENCE();
    __builtin_amdgcn_sched_barrier(0);
  }
  #undef STAGE_A
  #undef STAGE_B
}

// ---------------- K1: qkv GEMM + fused q-softmax / k-exp / per-block context partials ----------------
// grid 768 = 64 M-tiles x 12 N-tiles of 128 cols. tN 0..3: Q. tN 4..11: head h=tN-4 (K 0..63 | V 64..127)
__global__ __launch_bounds__(512, 2)
void k_qkv_gemm(const char* __restrict__ xb, const char* __restrict__ wqT,
                u16* __restrict__ qhat, float* __restrict__ ctx_part,
                float* __restrict__ z_part) {
  __shared__ __align__(16) char lds[147456];
  const int bx = blockIdx.x;
  const int tM = bx & 63, tN = bx >> 6;
  fx4 acc[4][4];
  const fx4 z4 = {0.f, 0.f, 0.f, 0.f};
  #pragma unroll
  for (int i = 0; i < 4; ++i)
    #pragma unroll
    for (int j = 0; j < 4; ++j) acc[i][j] = z4;

  gemm_core2(xb + tM * 262144, wqT + tN * 131072, lds, acc);

  const int t = threadIdx.x, w = t >> 6, l = t & 63;
  const int wm = w >> 1, wn = w & 1;
  const int m0 = tM * 256 + wm * 64;
  const int c0 = tN * 128 + wn * 64;

  if (tN < 4) {
    // q: softmax over the 64 head-dim cols (exactly this wave's col span)
    #pragma unroll
    for (int fm = 0; fm < 4; ++fm) {
      #pragma unroll
      for (int fn = 0; fn < 4; ++fn)
        #pragma unroll
        for (int r = 0; r < 4; ++r)
          acc[fm][fn][r] = __expf(acc[fm][fn][r]);
      fx4 s = acc[fm][0] + acc[fm][1] + acc[fm][2] + acc[fm][3];
      fx4 inv;
      #pragma unroll
      for (int r = 0; r < 4; ++r) {
        float sv = s[r];
        sv += __shfl_xor(sv, 1, 64);
        sv += __shfl_xor(sv, 2, 64);
        sv += __shfl_xor(sv, 4, 64);
        sv += __shfl_xor(sv, 8, 64);
        inv[r] = 1.0f / sv;
      }
      #pragma unroll
      for (int fn = 0; fn < 4; ++fn)
        #pragma unroll
        for (int r = 0; r < 4; ++r) {
          int m = m0 + fm * 16 + ((l >> 4) * 4) + r;
          int c = c0 + fn * 16 + (l & 15);
          qhat[m * 512 + c] = f2bf(acc[fm][fn][r] * inv[r]);
        }
    }
  } else {
    const int h = tN - 4;
    const int b = tM >> 4;
    const int mt = tM & 15;
    const int bh = b * 8 + h;
    char* ktb = lds;            // 64 d-rows x 256 n bf16, swizzled (32KB)
    char* vtb = lds + 32768;    // 32KB
    __syncthreads();
    {
      char* dstb = (wn == 0) ? ktb : vtb;
      const bool isK = (wn == 0);
      #pragma unroll
      for (int fm = 0; fm < 4; ++fm)
        #pragma unroll
        for (int fn = 0; fn < 4; ++fn) {
          int d = fn * 16 + (l & 15);
          int n0 = wm * 64 + fm * 16 + ((l >> 4) * 4);
          US4 p;
          #pragma unroll
          for (int r = 0; r < 4; ++r) {
            float v = acc[fm][fn][r];
            if (isK) { float tt = v > 0.f ? v + 1.f : __expf(v); v = __expf(tt); }
            p.v[r] = f2bf(v);
          }
          *(US4*)(dstb + d * 512 + ((2 * n0) ^ ((d & 7) << 4))) = p;
        }
    }
    __syncthreads();
    // ctx[d][e] = sum_n khat[d][n]*v[e][n]; wave: d-group wm (16 rows), e-half wn (32 cols)
    fx4 cacc[2]; fx4 zacc = z4;
    cacc[0] = z4; cacc[1] = z4;
    bhalf8 ones;
    #pragma unroll
    for (int i = 0; i < 8; ++i) ones[i] = (short)0x3F80;  // bf16 1.0
    #pragma unroll
    for (int kk = 0; kk < 8; ++kk) {
      int nbyte = kk * 64 + ((l >> 4) * 16);
      int d = wm * 16 + (l & 15);
      bhalf8 a = *(const bhalf8*)(ktb + d * 512 + (nbyte ^ ((d & 7) << 4)));
      #pragma unroll
      for (int fn = 0; fn < 2; ++fn) {
        int e = wn * 32 + fn * 16 + (l & 15);
        bhalf8 bv = *(const bhalf8*)(vtb + e * 512 + (nbyte ^ ((e & 7) << 4)));
        cacc[fn] = MFMA16(a, bv, cacc[fn]);
      }
      if (wn == 0) zacc = MFMA16(a, ones, zacc);
    }
    float* cp = ctx_part + (bh * 16 + mt) * 4096;
    #pragma unroll
    for (int fn = 0; fn < 2; ++fn)
      #pragma unroll
      for (int r = 0; r < 4; ++r) {
        int d = wm * 16 + ((l >> 4) * 4) + r;
        int e = wn * 32 + fn * 16 + (l & 15);
        cp[d * 64 + e] = cacc[fn][r];
      }
    if (wn == 0 && (l & 15) == 0) {
      #pragma unroll
      for (int r = 0; r < 4; ++r)
        z_part[(bh * 16 + mt) * 64 + wm * 16 + ((l >> 4) * 4) + r] = zacc[r];
    }
  }
}

// ---------------- K2: reduce ctx partials over the 16 M-blocks ----------------
__global__ __launch_bounds__(256)
void k_reduce(const float* __restrict__ ctx_part, float* __restrict__ ctx32) {
  const int bx = blockIdx.x;    // 512 = 32 bh x 16 slices
  const int bh = bx >> 4;
  const int idx = (bx & 15) * 256 + threadIdx.x;
  float s = 0.f;
  #pragma unroll
  for (int mt = 0; mt < 16; ++mt)
    s += ctx_part[(bh * 16 + mt) * 4096 + idx];
  ctx32[bh * 4096 + idx] = s;
}

// ---------------- K3: W2T[b][c][hd] = sum_e (ctx[d][e]/Z[d]) * wp[h*64+e][c]  (bf16 MFMA) ----------------
__global__ __launch_bounds__(256, 1)
void k_w2(const float* __restrict__ ctx32, const float* __restrict__ z_part,
          const u16* __restrict__ wpT, u16* __restrict__ W2T) {
  const int bh = blockIdx.x;            // 32
  const int b = bh >> 3, h = bh & 7;
  __shared__ float zinv[64];
  __shared__ __align__(16) u16 alds[64][72];
  const int t = threadIdx.x;
  if (t < 64) {
    float zs = 0.f;
    #pragma unroll
    for (int mt = 0; mt < 16; ++mt) zs += z_part[(bh * 16 + mt) * 64 + t];
    zinv[t] = 1.0f / zs;
  }
  __syncthreads();
  #pragma unroll
  for (int i = 0; i < 16; ++i) {
    int idx = i * 256 + t;
    int d = idx >> 6, e = idx & 63;
    alds[d][e] = f2bf(ctx32[bh * 4096 + idx] * zinv[d]);
  }
  __syncthreads();
  const int w = t >> 6, l = t & 63;
  fx4 acc[4][8];
  const fx4 z4 = {0.f, 0.f, 0.f, 0.f};
  #pragma unroll
  for (int i = 0; i < 4; ++i)
    #pragma unroll
    for (int j = 0; j < 8; ++j) acc[i][j] = z4;
  #pragma unroll
  for (int ks = 0; ks < 2; ++ks) {
    bhalf8 af[4];
    #pragma unroll
    for (int fm = 0; fm < 4; ++fm) {
      int row = fm * 16 + (l & 15);
      af[fm] = *(const bhalf8*)((const char*)alds + row * 144 + ks * 64 + ((l >> 4) * 16));
    }
    #pragma unroll
    for (int fn = 0; fn < 8; ++fn) {
      int c = w * 128 + fn * 16 + (l & 15);
      bhalf8 bv = *(const bhalf8*)(wpT + c * 512 + h * 64 + ks * 32 + ((l >> 4) * 8));
      #pragma unroll
      for (int fm = 0; fm < 4; ++fm)
        acc[fm][fn] = MFMA16(af[fm], bv, acc[fm][fn]);
    }
  }
  #pragma unroll
  for (int fm = 0; fm < 4; ++fm)
    #pragma unroll
    for (int fn = 0; fn < 8; ++fn) {
      int c = w * 128 + fn * 16 + (l & 15);
      int d0 = fm * 16 + ((l >> 4) * 4);
      US4 p;
      #pragma unroll
      for (int r = 0; r < 4; ++r) p.v[r] = f2bf(acc[fm][fn][r]);
      *(US4*)(W2T + (b * 512 + c) * 512 + h * 64 + d0) = p;
    }
}

// ---------------- K4: final GEMM  out = qhat @ W2_b + bias ----------------
// grid 256 = 64 M-tiles x 4 N-tiles of 128
__global__ __launch_bounds__(512, 2)
void k_out_gemm(const char* __restrict__ qhat, const char* __restrict__ W2T,
                const float* __restrict__ bproj, float* __restrict__ outp) {
  __shared__ __align__(16) char lds[147456];
  const int bx = blockIdx.x;
  const int tM = bx & 63, tN = bx >> 6;
  const int b = tM >> 4;
  fx4 acc[4][4];
  const fx4 z4 = {0.f, 0.f, 0.f, 0.f};
  #pragma unroll
  for (int i = 0; i < 4; ++i)
    #pragma unroll
    for (int j = 0; j < 4; ++j) acc[i][j] = z4;

  gemm_core2(qhat + tM * 262144, W2T + b * 524288 + tN * 131072, lds, acc);

  const int t = threadIdx.x, w = t >> 6, l = t & 63;
  const int wm = w >> 1, wn = w & 1;
  const int m0 = tM * 256 + wm * 64;
  const int c0 = tN * 128 + wn * 64;
  #pragma unroll
  for (int fm = 0; fm < 4; ++fm)
    #pragma unroll
    for (int fn = 0; fn < 4; ++fn) {
      int c = c0 + fn * 16 + (l & 15);
      float bp = bproj[c];
      #pragma unroll
      for (int r = 0; r < 4; ++r) {
        int m = m0 + fm * 16 + ((l >> 4) * 4) + r;
        outp[m * 512 + c] = acc[fm][fn][r] + bp;
      }
    }
}

extern "C" void kernel_launch(void* const* d_in, const int* in_sizes, int n_in,
                              void* d_out, int out_size, void* d_ws, size_t ws_size,
                              hipStream_t stream) {
  (void)in_sizes; (void)n_in; (void)out_size;
  const float* x     = (const float*)d_in[0];
  const float* wqkv  = (const float*)d_in[1];
  const float* wproj = (const float*)d_in[2];
  const float* bproj = (const float*)d_in[3];
  float* outp = (float*)d_out;
  char* ws = (char*)d_ws;

  char* xb   = ws;                 // 16384*512*2       = 16,777,216
  char* wqT  = ws + 16777216;      // 1536*512*2        =  1,572,864
  char* wpT  = ws + 18350080;      // 512*512*2         =    524,288
  char* qhat = ws + 18874368;      // 16384*512*2       = 16,777,216
  char* ctxp = ws + 35651584;      // 32*16*4096*4      =  8,388,608
  char* zp   = ws + 44040192;      // 32*16*64*4        =    131,072
  char* ctx32= ws + 44171264;      // 32*4096*4         =    524,288
  char* w2t  = ws + 44695552;      // 4*512*512*2       =  2,097,152  (end 46,792,704)
  if (ws_size < 46792704) return;

  k_conv<<<8192, 256, 0, stream>>>(x, (u16*)xb, 2097152);
  k_transpose<<<192, 256, 0, stream>>>(wqkv, (u16*)wqT, 512, 1536, 8, 1);
  k_transpose<<<64, 256, 0, stream>>>(wproj, (u16*)wpT, 512, 512, 8, 0);
  k_qkv_gemm<<<768, 512, 0, stream>>>(xb, wqT, (u16*)qhat, (float*)ctxp, (float*)zp);
  k_reduce<<<512, 256, 0, stream>>>((const float*)ctxp, (float*)ctx32);
  k_w2<<<32, 256, 0, stream>>>((const float*)ctx32, (const float*)zp, (const u16*)wpT, (u16*)w2t);
  k_out_gemm<<<256, 512, 0, stream>>>(qhat, w2t, bproj, outp);
}